// Round 1
// baseline (11814.771 us; speedup 1.0000x reference)
//
#include <hip/hip_runtime.h>

#define Tn 64
#define Bn 512
#define Dn 512
#define Hn 2048

typedef __attribute__((ext_vector_type(8))) short s16x8;
typedef __attribute__((ext_vector_type(4))) float f32x4;

__device__ __forceinline__ unsigned short f2bf(float f) {
    unsigned int u = __builtin_bit_cast(unsigned int, f);
    return (unsigned short)((u + 0x7fffu + ((u >> 16) & 1u)) >> 16);
}

// tanh(x) = 1 - 2/(exp2(x*2/ln2)+1); NaN-free at +-inf, ~1ulp from v_exp/v_rcp
__device__ __forceinline__ float tanh_fast(float x) {
    float e = __builtin_amdgcn_exp2f(x * 2.885390081777927f);
    return 1.0f - 2.0f * __builtin_amdgcn_rcpf(e + 1.0f);
}

// Pack W1 (512x2048) and W2 (2048x512), f32 row-major -> bf16 MFMA-B-fragment order:
// [ntile][ktile][lane][8], element (k,n): lane = (n%16) + 16*((k%32)/8), e = k%8.
__global__ void pack_w(const float* __restrict__ W1, const float* __restrict__ W2,
                       unsigned short* __restrict__ w1p, unsigned short* __restrict__ w2p) {
    const int i = blockIdx.x * 256 + threadIdx.x;   // 0 .. 2^20-1, both mats are 1M elems
    const int e = i & 7;
    const int lane = (i >> 3) & 63;
    const int krem = ((lane >> 4) << 3) + e;        // k within 32-wide k-tile
    const int ncol = lane & 15;
    {   // W1: K=512 (16 ktiles), N=2048 (128 ntiles)
        const int kt = (i >> 9) & 15, nt = i >> 13;
        const int k = (kt << 5) + krem, n = (nt << 4) + ncol;
        w1p[i] = f2bf(W1[k * Hn + n]);
    }
    {   // W2: K=2048 (64 ktiles), N=512 (32 ntiles)
        const int kt = (i >> 9) & 63, nt = i >> 15;
        const int k = (kt << 5) + krem, n = (nt << 4) + ncol;
        w2p[i] = f2bf(W2[k * Dn + n]);
    }
}

// 32 WGs x 512 threads (8 waves). WG owns 16 batch rows for all 63 RK4 steps.
// GEMM1: wave w -> H-slice [w*256, w*256+256). GEMM2: wave w -> D-slice [w*64, w*64+64).
__launch_bounds__(512, 2)
__global__ void ode_rk4(const float* __restrict__ y0, const float* __restrict__ tt,
                        const float* __restrict__ b1, const float* __restrict__ b2,
                        const unsigned short* __restrict__ w1p,
                        const unsigned short* __restrict__ w2p,
                        float* __restrict__ out) {
    __shared__ unsigned short lds_ys[16 * Dn];    // 16 KiB, stage input, bf16, XOR-swizzled
    __shared__ unsigned short lds_hid[16 * Hn];   // 64 KiB, tanh output, bf16, XOR-swizzled
    __shared__ float lds_dt[16];

    const int tid  = threadIdx.x;
    const int w    = tid >> 6;
    const int lane = tid & 63;
    const int l15  = lane & 15;
    const int kgrp = lane >> 4;
    const int row0 = blockIdx.x << 4;

    float yreg[4][4], ksum[4][4], kk[4][4];
    float b1v[16], b2v[4], dtv[4];

    #pragma unroll
    for (int nt = 0; nt < 16; ++nt) b1v[nt] = b1[(w << 8) + (nt << 4) + l15];
    #pragma unroll
    for (int c = 0; c < 4; ++c) b2v[c] = b2[(w << 6) + (c << 4) + l15];

    // init state from y0, and out[0] = y0
    #pragma unroll
    for (int c = 0; c < 4; ++c) {
        #pragma unroll
        for (int j = 0; j < 4; ++j) {
            const int r = (kgrp << 2) + j;
            const int col = (w << 6) + (c << 4) + l15;
            const float v = y0[(row0 + r) * Dn + col];
            yreg[c][j] = v;
            ksum[c][j] = 0.f;
            kk[c][j]   = 0.f;
            out[(row0 + r) * Dn + col] = v;
        }
    }

    const unsigned short* wv1 = w1p + ((w << 4) * (16 * 512)) + (lane << 3);
    const unsigned short* wv2 = w2p + ((w << 2) * (64 * 512)) + (lane << 3);
    const int arow = l15;
    const unsigned swzA = (unsigned)((arow & 7) << 3);

    for (int step = 0; step < Tn - 1; ++step) {
        if (tid < 16)
            lds_dt[tid] = tt[(step + 1) * Bn + row0 + tid] - tt[step * Bn + row0 + tid];

        #pragma unroll 1
        for (int s = 0; s < 4; ++s) {
            const float ci = (s == 3) ? 1.0f : ((s == 0) ? 0.0f : 0.5f);
            // stage input y + ci*k_prev -> lds_ys (bf16)
            #pragma unroll
            for (int c = 0; c < 4; ++c) {
                #pragma unroll
                for (int j = 0; j < 4; ++j) {
                    const int r = (kgrp << 2) + j;
                    const int col = (w << 6) + (c << 4) + l15;
                    const float yin = yreg[c][j] + ci * kk[c][j];
                    lds_ys[(unsigned)((r << 9) + col) ^ (unsigned)((r & 7) << 3)] = f2bf(yin);
                }
            }
            __syncthreads();
            if (s == 0) {
                #pragma unroll
                for (int j = 0; j < 4; ++j) dtv[j] = lds_dt[(kgrp << 2) + j];
            }

            // GEMM1: hidden = tanh(ys @ W1 + b1), wave covers 16 n-tiles, K=512
            f32x4 acc[16];
            #pragma unroll
            for (int nt = 0; nt < 16; ++nt) {
                #pragma unroll
                for (int j = 0; j < 4; ++j) acc[nt][j] = b1v[nt];
            }
            #pragma unroll 2
            for (int kt = 0; kt < 16; ++kt) {
                const unsigned ia = ((unsigned)((arow << 9) + (kt << 5) + (kgrp << 3))) ^ swzA;
                const s16x8 a = *(const s16x8*)&lds_ys[ia];
                #pragma unroll
                for (int nt = 0; nt < 16; ++nt) {
                    const s16x8 bfrag = *(const s16x8*)&wv1[nt * 8192 + kt * 512];
                    acc[nt] = __builtin_amdgcn_mfma_f32_16x16x32_bf16(a, bfrag, acc[nt], 0, 0, 0);
                }
            }
            #pragma unroll
            for (int nt = 0; nt < 16; ++nt) {
                #pragma unroll
                for (int j = 0; j < 4; ++j) {
                    const int r = (kgrp << 2) + j;
                    const int col = (w << 8) + (nt << 4) + l15;
                    lds_hid[(unsigned)((r << 11) + col) ^ (unsigned)((r & 7) << 3)] =
                        f2bf(tanh_fast(acc[nt][j]));
                }
            }
            __syncthreads();

            // GEMM2: k = dt * (hidden @ W2 + b2), wave covers 4 n-tiles, K=2048
            f32x4 acc2[4];
            #pragma unroll
            for (int c = 0; c < 4; ++c) {
                #pragma unroll
                for (int j = 0; j < 4; ++j) acc2[c][j] = 0.f;
            }
            #pragma unroll 2
            for (int kt = 0; kt < 64; ++kt) {
                const unsigned ia = ((unsigned)((arow << 11) + (kt << 5) + (kgrp << 3))) ^ swzA;
                const s16x8 a = *(const s16x8*)&lds_hid[ia];
                #pragma unroll
                for (int c = 0; c < 4; ++c) {
                    const s16x8 bfrag = *(const s16x8*)&wv2[c * 32768 + kt * 512];
                    acc2[c] = __builtin_amdgcn_mfma_f32_16x16x32_bf16(a, bfrag, acc2[c], 0, 0, 0);
                }
            }
            const float wq = (s == 0 || s == 3) ? 1.0f : 2.0f;
            #pragma unroll
            for (int c = 0; c < 4; ++c) {
                #pragma unroll
                for (int j = 0; j < 4; ++j) {
                    const float kv = dtv[j] * (acc2[c][j] + b2v[c]);
                    kk[c][j] = kv;
                    ksum[c][j] = (s == 0) ? kv : ksum[c][j] + wq * kv;
                }
            }
        }

        // y += ksum/6; emit out[step+1]
        #pragma unroll
        for (int c = 0; c < 4; ++c) {
            #pragma unroll
            for (int j = 0; j < 4; ++j) {
                const int r = (kgrp << 2) + j;
                const int col = (w << 6) + (c << 4) + l15;
                yreg[c][j] += ksum[c][j] * (1.0f / 6.0f);
                out[((step + 1) * Bn + row0 + r) * Dn + col] = yreg[c][j];
            }
        }
    }
}

extern "C" void kernel_launch(void* const* d_in, const int* in_sizes, int n_in,
                              void* d_out, int out_size, void* d_ws, size_t ws_size,
                              hipStream_t stream) {
    const float* y0 = (const float*)d_in[0];
    const float* tt = (const float*)d_in[1];
    const float* W1 = (const float*)d_in[2];
    const float* b1 = (const float*)d_in[3];
    const float* W2 = (const float*)d_in[4];
    const float* b2 = (const float*)d_in[5];
    unsigned short* w1p = (unsigned short*)d_ws;            // 2 MiB
    unsigned short* w2p = w1p + (size_t)Dn * Hn;            // 2 MiB
    float* out = (float*)d_out;

    pack_w<<<4096, 256, 0, stream>>>(W1, W2, w1p, w2p);
    ode_rk4<<<32, 512, 0, stream>>>(y0, tt, b1, b2, w1p, w2p, out);
}